// Round 21
// baseline (63.555 us; speedup 1.0000x reference)
//
#include <hip/hip_runtime.h>
#include <hip/hip_bf16.h>
#include <stdint.h>

typedef __hip_bfloat16 bf16;
typedef float f32x4 __attribute__((ext_vector_type(4)));
typedef short bf16x8 __attribute__((ext_vector_type(8)));

#define NB 16384
#define NA 16
#define ND 512
#define NH 512
#define TR 48  // rows/tile: ~22 tiles/action, ~44/XCD-pair <= 64 slots (2 blocks/CU)

// workspace layout (bytes)
#define W1S_OFF 0u
#define W2S_OFF 8388608u
#define PERM_OFF 16777216u
#define META_OFF 16842752u
// meta ints: [0..15]=cnt, [16..31]=off

__device__ __forceinline__ unsigned short f2b(float x) {
  unsigned int b = __float_as_uint(x);
  return (unsigned short)((b + 0x7FFFu + ((b >> 16) & 1u)) >> 16);  // RNE
}

// ---------------- prep: W transpose+cast (blocks 0..2047) + parallel meta (block 2048) -----
// (byte-identical to round 20's k_prep)
__global__ __launch_bounds__(256) void k_prep(const float* __restrict__ W1,
                                              const float* __restrict__ W2,
                                              bf16* __restrict__ W1s,
                                              bf16* __restrict__ W2s,
                                              const int* __restrict__ act,
                                              int* __restrict__ meta,
                                              int* __restrict__ perm) {
  __shared__ union {
    float tile[64][65];
    struct { int hist[16][256]; int off16[16]; } m;
  } lds;
  if (blockIdx.x == 2048) {
    int t = threadIdx.x;
    int lane = t & 63, wv = t >> 6;
#pragma unroll
    for (int i = 0; i < 16; ++i) lds.m.hist[i][t] = 0;
    __syncthreads();
    for (int j = 0; j < 64; ++j) {
      int a = act[t + (j << 8)] & 15;
      lds.m.hist[a][t]++;
    }
    __syncthreads();
    for (int q = 0; q < 4; ++q) {
      int a = (wv << 2) + q;
      int base = lane << 2;
      int v0 = lds.m.hist[a][base + 0];
      int v1 = lds.m.hist[a][base + 1];
      int v2 = lds.m.hist[a][base + 2];
      int v3 = lds.m.hist[a][base + 3];
      int s = v0 + v1 + v2 + v3;
      int incl = s;
#pragma unroll
      for (int d = 1; d < 64; d <<= 1) {
        int y = __shfl_up(incl, d);
        if (lane >= d) incl += y;
      }
      int excl = incl - s;
      lds.m.hist[a][base + 0] = excl;
      lds.m.hist[a][base + 1] = excl + v0;
      lds.m.hist[a][base + 2] = excl + v0 + v1;
      lds.m.hist[a][base + 3] = excl + v0 + v1 + v2;
      if (lane == 63) lds.m.off16[a] = incl;
    }
    __syncthreads();
    if (t == 0) {
      int o = 0;
      for (int aa = 0; aa < 16; ++aa) {
        int c = lds.m.off16[aa];
        meta[aa] = c;
        meta[16 + aa] = o;
        lds.m.off16[aa] = o;
        o += c;
      }
    }
    __syncthreads();
    for (int j = 0; j < 64; ++j) {
      int idx = t + (j << 8);
      int a = act[idx] & 15;
      int pos = lds.m.off16[a] + lds.m.hist[a][t]++;
      perm[pos] = idx;
    }
    return;
  }
  int j = blockIdx.x;            // 0..2047
  int xcd = j & 7;
  int job = j >> 3;              // 0..255
  int mi = job >> 6;             // 0..3: W1[2x], W1[2x+1], W2[2x], W2[2x+1]
  int m = (mi < 2) ? ((xcd << 1) + mi) : (NA + (xcd << 1) + (mi - 2));
  int tl = job & 63;
  int td = tl >> 3, th = tl & 7; // td: k-tile, th: h-tile
  const float* src = (m < NA) ? (W1 + (size_t)m * (ND * NH)) : (W2 + (size_t)(m - NA) * (ND * NH));
  char* dstb = (m < NA) ? ((char*)W1s + ((size_t)m << 19)) : ((char*)W2s + ((size_t)(m - NA) << 19));
  int t = threadIdx.x;
  int r = t >> 2, c0 = (t & 3) << 4;
  const float* sp = src + (size_t)(td * 64 + r) * NH + th * 64 + c0;
  float4 v0 = ((const float4*)sp)[0];
  float4 v1 = ((const float4*)sp)[1];
  float4 v2 = ((const float4*)sp)[2];
  float4 v3 = ((const float4*)sp)[3];
  float* tr = &lds.tile[r][c0];
  tr[0] = v0.x; tr[1] = v0.y; tr[2] = v0.z; tr[3] = v0.w;
  tr[4] = v1.x; tr[5] = v1.y; tr[6] = v1.z; tr[7] = v1.w;
  tr[8] = v2.x; tr[9] = v2.y; tr[10] = v2.z; tr[11] = v2.w;
  tr[12] = v3.x; tr[13] = v3.y; tr[14] = v3.z; tr[15] = v3.w;
  __syncthreads();
  int wv = t >> 6, l = t & 63;
  int l15b = l & 15, l4b = l >> 4;
#pragma unroll
  for (int kc = 0; kc < 2; ++kc) {
    union { unsigned short us[8]; uint4 q; } u;
#pragma unroll
    for (int i = 0; i < 8; ++i)
      u.us[i] = f2b(lds.tile[kc * 32 + l4b * 8 + i][wv * 16 + l15b]);
    int hb = th * 4 + wv;   // global h>>4
    int kb = td * 2 + kc;   // global k>>5
    *(uint4*)(dstb + ((size_t)(hb * 16 + kb) << 10) + (l << 4)) = u.q;
  }
}

// ---------------- fused grouped MLP: 2 independent blocks/CU ----------------
// TR=48, 512 threads = 8 waves, wave w owns h [w*64,+64) (hf=4) x all 48 cols (bf=3).
// LDS 49.6KB -> 2 blocks/CU (16 waves/CU total) with INDEPENDENT barriers: block B's
// MFMA fills block A's staging/barrier stalls (R5 vs R13 showed lockstep waves trade
// TLP vs LDS-traffic 1:1; splitting into 2 blocks breaks the lockstep).
// VGPR: acc48+A32+Bc12+h1p24+addr ~= 120 <= 128 cap via (512,2) [validated R3/R5].
// XCD x (bid&7) owns actions 2x,2x+1. Grid 512 = 64 slots/XCD >= ~44 tiles/pair.
// LDS: Xs 48KB @0 (X, then h1 via register round-trip), outbuf 1.5KB @49152.
__global__ __launch_bounds__(512, 2) void k_main(
    const float* __restrict__ state, const float* __restrict__ b1,
    const float* __restrict__ b2, const float* __restrict__ W3,
    const float* __restrict__ b3, const bf16* __restrict__ W1s,
    const bf16* __restrict__ W2s, const int* __restrict__ perm,
    const int* __restrict__ meta, float* __restrict__ out) {
  extern __shared__ char smem[];
  char* Xs = smem;
  float* outbuf = (float*)(smem + 49152);

  int bid = blockIdx.x;
  int xcd = bid & 7, slot = bid >> 3;  // slot 0..63
  int a0 = xcd << 1;
  int n0 = meta[a0], n1 = meta[a0 + 1];
  int nt0 = (n0 + TR - 1) / TR, nt1 = (n1 + TR - 1) / TR;
  int a, t;
  if (slot < nt0) {
    a = a0; t = slot;
  } else if (slot < nt0 + nt1) {
    a = a0 + 1; t = slot - nt0;
  } else {
    return;
  }
  int rowbase = meta[16 + a] + t * TR;
  int nrows = meta[a] - t * TR;
  nrows = nrows > TR ? TR : nrows;

  int tid = threadIdx.x;
  int lane = tid & 63;
  int w = tid >> 6;  // 0..7; h-group [w*64, w*64+64)
  int l15 = lane & 15, l4 = lane >> 4;

  // A blob addr: base + ((h>>4)*16 + ks)*1024 + lane*16, h>>4 = w*4 + hf
  const char* Wl = (const char*)W1s + ((size_t)a << 19) + (w << 16) + (lane << 4);
  const char* Wl2 = (const char*)W2s + ((size_t)a << 19) + (w << 16) + (lane << 4);

  bf16x8 A[2][4];  // [ks&1][hf] depth-2 pipeline
  bf16x8 Bc[3];
#pragma unroll
  for (int s = 0; s < 2; ++s)
#pragma unroll
    for (int hf = 0; hf < 4; ++hf)
      A[s][hf] = *(const bf16x8*)(Wl + (hf << 14) + (s << 10));

  // ---- stage X tile -> LDS bf16, swizzle byte ^= (row&7)<<4 ----
  {
#pragma unroll
    for (int it = 0; it < 12; ++it) {
      int c = tid + (it << 9);       // 0..6143
      int row = c >> 7, chunk = c & 127;
      int gr = (row < nrows) ? perm[rowbase + row] : -1;
      float4 v = make_float4(0.f, 0.f, 0.f, 0.f);
      if (gr >= 0) v = *(const float4*)(state + (size_t)gr * ND + (chunk << 2));
      uint2 pk;
      pk.x = (unsigned)f2b(v.x) | ((unsigned)f2b(v.y) << 16);
      pk.y = (unsigned)f2b(v.z) | ((unsigned)f2b(v.w) << 16);
      *(uint2*)(Xs + row * 1024 + ((chunk << 3) ^ ((row & 7) << 4))) = pk;
    }
  }
  __syncthreads();

  uint2 h1p[12];

  // ---- layer 1: h1 = relu(X @ W1 + b1), [h][b], h1 kept in registers ----
  {
    f32x4 acc[4][3] = {};
#pragma unroll
    for (int ks = 0; ks < 16; ++ks) {
#pragma unroll
      for (int bf = 0; bf < 3; ++bf) {
        int b = (bf << 4) + l15;
        Bc[bf] = *(const bf16x8*)(Xs + b * 1024 + (((ks << 6) + (l4 << 4)) ^ ((b & 7) << 4)));
      }
      __builtin_amdgcn_s_setprio(1);
#pragma unroll
      for (int hf = 0; hf < 4; ++hf)
#pragma unroll
        for (int bf = 0; bf < 3; ++bf)
          acc[hf][bf] = __builtin_amdgcn_mfma_f32_16x16x32_bf16(A[ks & 1][hf], Bc[bf], acc[hf][bf], 0, 0, 0);
      __builtin_amdgcn_s_setprio(0);
      if (ks < 14) {
#pragma unroll
        for (int hf = 0; hf < 4; ++hf)
          A[ks & 1][hf] = *(const bf16x8*)(Wl + (hf << 14) + ((ks + 2) << 10));
      }
    }
    // layer-2 A preloads; latency hides under epilogue + barriers
#pragma unroll
    for (int s = 0; s < 2; ++s)
#pragma unroll
      for (int hf = 0; hf < 4; ++hf)
        A[s][hf] = *(const bf16x8*)(Wl2 + (hf << 14) + (s << 10));
    // epilogue: bias + relu + pack bf16 into registers
#pragma unroll
    for (int hf = 0; hf < 4; ++hf) {
      int hb = (w << 6) + (hf << 4) + (l4 << 2);
      float4 bias = *(const float4*)(b1 + (a << 9) + hb);
#pragma unroll
      for (int bf = 0; bf < 3; ++bf) {
        float x0 = fmaxf(acc[hf][bf][0] + bias.x, 0.f);
        float x1 = fmaxf(acc[hf][bf][1] + bias.y, 0.f);
        float x2 = fmaxf(acc[hf][bf][2] + bias.z, 0.f);
        float x3 = fmaxf(acc[hf][bf][3] + bias.w, 0.f);
        h1p[hf * 3 + bf].x = (unsigned)f2b(x0) | ((unsigned)f2b(x1) << 16);
        h1p[hf * 3 + bf].y = (unsigned)f2b(x2) | ((unsigned)f2b(x3) << 16);
      }
    }
  }
  __syncthreads();  // all waves done reading X
#pragma unroll
  for (int hf = 0; hf < 4; ++hf) {
    int hb2 = ((w << 6) + (hf << 4) + (l4 << 2)) << 1;  // byte offset within row
#pragma unroll
    for (int bf = 0; bf < 3; ++bf) {
      int b = (bf << 4) + l15;
      *(uint2*)(Xs + b * 1024 + (hb2 ^ ((b & 7) << 4))) = h1p[hf * 3 + bf];
    }
  }
  __syncthreads();

  // ---- layer 2 + fused layer 3: out = relu(h1 @ W2 + b2) . W3 + b3 ----
  {
    f32x4 acc[4][3] = {};
#pragma unroll
    for (int ks = 0; ks < 16; ++ks) {
#pragma unroll
      for (int bf = 0; bf < 3; ++bf) {
        int b = (bf << 4) + l15;
        Bc[bf] = *(const bf16x8*)(Xs + b * 1024 + (((ks << 6) + (l4 << 4)) ^ ((b & 7) << 4)));
      }
      __builtin_amdgcn_s_setprio(1);
#pragma unroll
      for (int hf = 0; hf < 4; ++hf)
#pragma unroll
        for (int bf = 0; bf < 3; ++bf)
          acc[hf][bf] = __builtin_amdgcn_mfma_f32_16x16x32_bf16(A[ks & 1][hf], Bc[bf], acc[hf][bf], 0, 0, 0);
      __builtin_amdgcn_s_setprio(0);
      if (ks < 14) {
#pragma unroll
        for (int hf = 0; hf < 4; ++hf)
          A[ks & 1][hf] = *(const bf16x8*)(Wl2 + (hf << 14) + ((ks + 2) << 10));
      }
    }
    float part[3] = {0.f, 0.f, 0.f};
#pragma unroll
    for (int hf = 0; hf < 4; ++hf) {
      int hb = (w << 6) + (hf << 4) + (l4 << 2);
      float4 bias = *(const float4*)(b2 + (a << 9) + hb);
      float4 w3v = *(const float4*)(W3 + (a << 9) + hb);
#pragma unroll
      for (int bf = 0; bf < 3; ++bf) {
        part[bf] += fmaxf(acc[hf][bf][0] + bias.x, 0.f) * w3v.x +
                    fmaxf(acc[hf][bf][1] + bias.y, 0.f) * w3v.y +
                    fmaxf(acc[hf][bf][2] + bias.z, 0.f) * w3v.z +
                    fmaxf(acc[hf][bf][3] + bias.w, 0.f) * w3v.w;
      }
    }
#pragma unroll
    for (int bf = 0; bf < 3; ++bf) {
      float p = part[bf];
      p += __shfl_xor(p, 16);
      p += __shfl_xor(p, 32);
      if (l4 == 0) outbuf[w * TR + (bf << 4) + l15] = p;
    }
  }
  __syncthreads();
  if (tid < nrows) {
    float s = b3[a];
#pragma unroll
    for (int ww = 0; ww < 8; ++ww) s += outbuf[ww * TR + tid];
    out[perm[rowbase + tid]] = s;
  }
}

extern "C" void kernel_launch(void* const* d_in, const int* in_sizes, int n_in,
                              void* d_out, int out_size, void* d_ws, size_t ws_size,
                              hipStream_t stream) {
  const float* state = (const float*)d_in[0];
  const float* W1 = (const float*)d_in[1];
  const float* b1 = (const float*)d_in[2];
  const float* W2 = (const float*)d_in[3];
  const float* b2 = (const float*)d_in[4];
  const float* W3 = (const float*)d_in[5];
  const float* b3 = (const float*)d_in[6];
  const int* actions = (const int*)d_in[7];
  float* out = (float*)d_out;
  char* ws = (char*)d_ws;
  bf16* W1s = (bf16*)(ws + W1S_OFF);
  bf16* W2s = (bf16*)(ws + W2S_OFF);
  int* perm = (int*)(ws + PERM_OFF);
  int* meta = (int*)(ws + META_OFF);

  k_prep<<<2049, 256, 0, stream>>>(W1, W2, W1s, W2s, actions, meta, perm);
  hipFuncSetAttribute((const void*)k_main, hipFuncAttributeMaxDynamicSharedMemorySize, 50688);
  k_main<<<512, 512, 50688, stream>>>(state, b1, b2, W3, b3, W1s, W2s, perm, meta, out);
}

// Round 22
// 48.561 us; speedup vs baseline: 1.3088x; 1.3088x over previous
//
#include <hip/hip_runtime.h>
#include <hip/hip_bf16.h>
#include <stdint.h>

typedef __hip_bfloat16 bf16;
typedef float f32x4 __attribute__((ext_vector_type(4)));
typedef short bf16x8 __attribute__((ext_vector_type(8)));

#define NB 16384
#define NA 16
#define ND 512
#define NH 512
#define TR 80  // rows/tile: 13-14 tiles/action, <=28/XCD-pair <= 32 CUs -> no tail

// workspace layout (bytes)
#define W1S_OFF 0u
#define W2S_OFF 8388608u
#define PERM_OFF 16777216u
#define META_OFF 16842752u
// meta ints: [0..15]=cnt, [16..31]=off

__device__ __forceinline__ unsigned short f2b(float x) {
  unsigned int b = __float_as_uint(x);
  return (unsigned short)((b + 0x7FFFu + ((b >> 16) & 1u)) >> 16);  // RNE
}

// ---------------- prep: W transpose+cast (blocks 0..2047) + parallel meta (block 2048) -----
__global__ __launch_bounds__(256) void k_prep(const float* __restrict__ W1,
                                              const float* __restrict__ W2,
                                              bf16* __restrict__ W1s,
                                              bf16* __restrict__ W2s,
                                              const int* __restrict__ act,
                                              int* __restrict__ meta,
                                              int* __restrict__ perm) {
  __shared__ union {
    float tile[64][65];
    struct { int hist[16][256]; int off16[16]; } m;
  } lds;
  if (blockIdx.x == 2048) {
    int t = threadIdx.x;
    int lane = t & 63, wv = t >> 6;
#pragma unroll
    for (int i = 0; i < 16; ++i) lds.m.hist[i][t] = 0;
    __syncthreads();
    for (int j = 0; j < 64; ++j) {
      int a = act[t + (j << 8)] & 15;
      lds.m.hist[a][t]++;
    }
    __syncthreads();
    for (int q = 0; q < 4; ++q) {
      int a = (wv << 2) + q;
      int base = lane << 2;
      int v0 = lds.m.hist[a][base + 0];
      int v1 = lds.m.hist[a][base + 1];
      int v2 = lds.m.hist[a][base + 2];
      int v3 = lds.m.hist[a][base + 3];
      int s = v0 + v1 + v2 + v3;
      int incl = s;
#pragma unroll
      for (int d = 1; d < 64; d <<= 1) {
        int y = __shfl_up(incl, d);
        if (lane >= d) incl += y;
      }
      int excl = incl - s;
      lds.m.hist[a][base + 0] = excl;
      lds.m.hist[a][base + 1] = excl + v0;
      lds.m.hist[a][base + 2] = excl + v0 + v1;
      lds.m.hist[a][base + 3] = excl + v0 + v1 + v2;
      if (lane == 63) lds.m.off16[a] = incl;
    }
    __syncthreads();
    if (t == 0) {
      int o = 0;
      for (int aa = 0; aa < 16; ++aa) {
        int c = lds.m.off16[aa];
        meta[aa] = c;
        meta[16 + aa] = o;
        lds.m.off16[aa] = o;
        o += c;
      }
    }
    __syncthreads();
    for (int j = 0; j < 64; ++j) {
      int idx = t + (j << 8);
      int a = act[idx] & 15;
      int pos = lds.m.off16[a] + lds.m.hist[a][t]++;
      perm[pos] = idx;
    }
    return;
  }
  int j = blockIdx.x;            // 0..2047
  int xcd = j & 7;
  int job = j >> 3;              // 0..255
  int mi = job >> 6;             // 0..3: W1[2x], W1[2x+1], W2[2x], W2[2x+1]
  int m = (mi < 2) ? ((xcd << 1) + mi) : (NA + (xcd << 1) + (mi - 2));
  int tl = job & 63;
  int td = tl >> 3, th = tl & 7; // td: k-tile, th: h-tile
  const float* src = (m < NA) ? (W1 + (size_t)m * (ND * NH)) : (W2 + (size_t)(m - NA) * (ND * NH));
  char* dstb = (m < NA) ? ((char*)W1s + ((size_t)m << 19)) : ((char*)W2s + ((size_t)(m - NA) << 19));
  int t = threadIdx.x;
  int r = t >> 2, c0 = (t & 3) << 4;
  const float* sp = src + (size_t)(td * 64 + r) * NH + th * 64 + c0;
  float4 v0 = ((const float4*)sp)[0];
  float4 v1 = ((const float4*)sp)[1];
  float4 v2 = ((const float4*)sp)[2];
  float4 v3 = ((const float4*)sp)[3];
  float* tr = &lds.tile[r][c0];
  tr[0] = v0.x; tr[1] = v0.y; tr[2] = v0.z; tr[3] = v0.w;
  tr[4] = v1.x; tr[5] = v1.y; tr[6] = v1.z; tr[7] = v1.w;
  tr[8] = v2.x; tr[9] = v2.y; tr[10] = v2.z; tr[11] = v2.w;
  tr[12] = v3.x; tr[13] = v3.y; tr[14] = v3.z; tr[15] = v3.w;
  __syncthreads();
  int wv = t >> 6, l = t & 63;
  int l15b = l & 15, l4b = l >> 4;
#pragma unroll
  for (int kc = 0; kc < 2; ++kc) {
    union { unsigned short us[8]; uint4 q; } u;
#pragma unroll
    for (int i = 0; i < 8; ++i)
      u.us[i] = f2b(lds.tile[kc * 32 + l4b * 8 + i][wv * 16 + l15b]);
    int hb = th * 4 + wv;   // global h>>4
    int kb = td * 2 + kc;   // global k>>5
    *(uint4*)(dstb + ((size_t)(hb * 16 + kb) << 10) + (l << 4)) = u.q;
  }
}

// ---------------- fused grouped MLP (round-13/18 geometry, best known: 48.6us) ------------
// XCD x (bid&7) owns actions 2x,2x+1 (2MB L2 set). Grid 256 = 32 slots/XCD, 26 tiles/pair.
// Block: 80-row tile, 1024 threads = 16 waves; wave w owns h [w*32, w*32+32).
// LDS: Xs 80KB @0 (X, then h1 via register round-trip), outbuf 5KB @81920.
__global__ __launch_bounds__(1024, 4) void k_main(
    const float* __restrict__ state, const float* __restrict__ b1,
    const float* __restrict__ b2, const float* __restrict__ W3,
    const float* __restrict__ b3, const bf16* __restrict__ W1s,
    const bf16* __restrict__ W2s, const int* __restrict__ perm,
    const int* __restrict__ meta, float* __restrict__ out) {
  extern __shared__ char smem[];
  char* Xs = smem;
  float* outbuf = (float*)(smem + 81920);

  int bid = blockIdx.x;
  int xcd = bid & 7, slot = bid >> 3;
  int a0 = xcd << 1;
  int n0 = meta[a0], n1 = meta[a0 + 1];
  int nt0 = (n0 + TR - 1) / TR, nt1 = (n1 + TR - 1) / TR;
  int a, t;
  if (slot < nt0) {
    a = a0; t = slot;
  } else if (slot < nt0 + nt1) {
    a = a0 + 1; t = slot - nt0;
  } else {
    return;
  }
  int rowbase = meta[16 + a] + t * TR;
  int nrows = meta[a] - t * TR;
  nrows = nrows > TR ? TR : nrows;

  int tid = threadIdx.x;
  int lane = tid & 63;
  int w = tid >> 6;  // 0..15
  int l15 = lane & 15, l4 = lane >> 4;

  // A blob addr: base + ((h>>4)*16 + ks)*1024 + lane*16, h>>4 = w*2 + hf
  const char* Wl = (const char*)W1s + ((size_t)a << 19) + (w << 15) + (lane << 4);
  const char* Wl2 = (const char*)W2s + ((size_t)a << 19) + (w << 15) + (lane << 4);

  bf16x8 A[2][2];  // [ks&1][hf] depth-2 pipeline
  bf16x8 Bc[5], Bn[5];
#pragma unroll
  for (int s = 0; s < 2; ++s)
#pragma unroll
    for (int hf = 0; hf < 2; ++hf)
      A[s][hf] = *(const bf16x8*)(Wl + (hf << 14) + (s << 10));

  // ---- stage X tile -> LDS bf16, swizzle byte ^= (row&7)<<4 ----
  {
#pragma unroll
    for (int it = 0; it < 10; ++it) {
      int c = tid + (it << 10);      // 0..10239
      int row = c >> 7, chunk = c & 127;
      int gr = (row < nrows) ? perm[rowbase + row] : -1;
      float4 v = make_float4(0.f, 0.f, 0.f, 0.f);
      if (gr >= 0) v = *(const float4*)(state + (size_t)gr * ND + (chunk << 2));
      uint2 pk;
      pk.x = (unsigned)f2b(v.x) | ((unsigned)f2b(v.y) << 16);
      pk.y = (unsigned)f2b(v.z) | ((unsigned)f2b(v.w) << 16);
      *(uint2*)(Xs + row * 1024 + ((chunk << 3) ^ ((row & 7) << 4))) = pk;
    }
  }
  __syncthreads();

  uint2 h1p[10];

  // ---- layer 1: h1 = relu(X @ W1 + b1), [h][b], h1 kept in registers ----
  {
    f32x4 acc[2][5] = {};
#pragma unroll
    for (int bf = 0; bf < 5; ++bf) {
      int b = (bf << 4) + l15;
      Bc[bf] = *(const bf16x8*)(Xs + b * 1024 + ((l4 << 4) ^ ((b & 7) << 4)));
    }
#pragma unroll
    for (int ks = 0; ks < 16; ++ks) {
      if (ks < 15) {
#pragma unroll
        for (int bf = 0; bf < 5; ++bf) {
          int b = (bf << 4) + l15;
          Bn[bf] = *(const bf16x8*)(Xs + b * 1024 + ((((ks + 1) << 6) + (l4 << 4)) ^ ((b & 7) << 4)));
        }
      }
#pragma unroll
      for (int hf = 0; hf < 2; ++hf)
#pragma unroll
        for (int bf = 0; bf < 5; ++bf)
          acc[hf][bf] = __builtin_amdgcn_mfma_f32_16x16x32_bf16(A[ks & 1][hf], Bc[bf], acc[hf][bf], 0, 0, 0);
      if (ks < 14) {
#pragma unroll
        for (int hf = 0; hf < 2; ++hf)
          A[ks & 1][hf] = *(const bf16x8*)(Wl + (hf << 14) + ((ks + 2) << 10));
      }
#pragma unroll
      for (int bf = 0; bf < 5; ++bf) Bc[bf] = Bn[bf];
    }
    // layer-2 A preloads; latency hides under epilogue + barriers
#pragma unroll
    for (int s = 0; s < 2; ++s)
#pragma unroll
      for (int hf = 0; hf < 2; ++hf)
        A[s][hf] = *(const bf16x8*)(Wl2 + (hf << 14) + (s << 10));
    // epilogue: bias + relu + pack bf16 into registers
#pragma unroll
    for (int hf = 0; hf < 2; ++hf) {
      int hb = (w << 5) + (hf << 4) + (l4 << 2);
      float4 bias = *(const float4*)(b1 + (a << 9) + hb);
#pragma unroll
      for (int bf = 0; bf < 5; ++bf) {
        float x0 = fmaxf(acc[hf][bf][0] + bias.x, 0.f);
        float x1 = fmaxf(acc[hf][bf][1] + bias.y, 0.f);
        float x2 = fmaxf(acc[hf][bf][2] + bias.z, 0.f);
        float x3 = fmaxf(acc[hf][bf][3] + bias.w, 0.f);
        h1p[hf * 5 + bf].x = (unsigned)f2b(x0) | ((unsigned)f2b(x1) << 16);
        h1p[hf * 5 + bf].y = (unsigned)f2b(x2) | ((unsigned)f2b(x3) << 16);
      }
    }
  }
  __syncthreads();  // all waves done reading X
#pragma unroll
  for (int hf = 0; hf < 2; ++hf) {
    int hb2 = ((w << 5) + (hf << 4) + (l4 << 2)) << 1;  // byte offset within row
#pragma unroll
    for (int bf = 0; bf < 5; ++bf) {
      int b = (bf << 4) + l15;
      *(uint2*)(Xs + b * 1024 + (hb2 ^ ((b & 7) << 4))) = h1p[hf * 5 + bf];
    }
  }
  __syncthreads();

  // ---- layer 2 + fused layer 3: out = relu(h1 @ W2 + b2) . W3 + b3 ----
  {
    f32x4 acc[2][5] = {};
#pragma unroll
    for (int bf = 0; bf < 5; ++bf) {
      int b = (bf << 4) + l15;
      Bc[bf] = *(const bf16x8*)(Xs + b * 1024 + ((l4 << 4) ^ ((b & 7) << 4)));
    }
#pragma unroll
    for (int ks = 0; ks < 16; ++ks) {
      if (ks < 15) {
#pragma unroll
        for (int bf = 0; bf < 5; ++bf) {
          int b = (bf << 4) + l15;
          Bn[bf] = *(const bf16x8*)(Xs + b * 1024 + ((((ks + 1) << 6) + (l4 << 4)) ^ ((b & 7) << 4)));
        }
      }
#pragma unroll
      for (int hf = 0; hf < 2; ++hf)
#pragma unroll
        for (int bf = 0; bf < 5; ++bf)
          acc[hf][bf] = __builtin_amdgcn_mfma_f32_16x16x32_bf16(A[ks & 1][hf], Bc[bf], acc[hf][bf], 0, 0, 0);
      if (ks < 14) {
#pragma unroll
        for (int hf = 0; hf < 2; ++hf)
          A[ks & 1][hf] = *(const bf16x8*)(Wl2 + (hf << 14) + ((ks + 2) << 10));
      }
#pragma unroll
      for (int bf = 0; bf < 5; ++bf) Bc[bf] = Bn[bf];
    }
    float part[5] = {0.f, 0.f, 0.f, 0.f, 0.f};
#pragma unroll
    for (int hf = 0; hf < 2; ++hf) {
      int hb = (w << 5) + (hf << 4) + (l4 << 2);
      float4 bias = *(const float4*)(b2 + (a << 9) + hb);
      float4 w3v = *(const float4*)(W3 + (a << 9) + hb);
#pragma unroll
      for (int bf = 0; bf < 5; ++bf) {
        part[bf] += fmaxf(acc[hf][bf][0] + bias.x, 0.f) * w3v.x +
                    fmaxf(acc[hf][bf][1] + bias.y, 0.f) * w3v.y +
                    fmaxf(acc[hf][bf][2] + bias.z, 0.f) * w3v.z +
                    fmaxf(acc[hf][bf][3] + bias.w, 0.f) * w3v.w;
      }
    }
#pragma unroll
    for (int bf = 0; bf < 5; ++bf) {
      float p = part[bf];
      p += __shfl_xor(p, 16);
      p += __shfl_xor(p, 32);
      if (l4 == 0) outbuf[w * TR + (bf << 4) + l15] = p;
    }
  }
  __syncthreads();
  if (tid < nrows) {
    float s = b3[a];
#pragma unroll
    for (int ww = 0; ww < 16; ++ww) s += outbuf[ww * TR + tid];
    out[perm[rowbase + tid]] = s;
  }
}

extern "C" void kernel_launch(void* const* d_in, const int* in_sizes, int n_in,
                              void* d_out, int out_size, void* d_ws, size_t ws_size,
                              hipStream_t stream) {
  const float* state = (const float*)d_in[0];
  const float* W1 = (const float*)d_in[1];
  const float* b1 = (const float*)d_in[2];
  const float* W2 = (const float*)d_in[3];
  const float* b2 = (const float*)d_in[4];
  const float* W3 = (const float*)d_in[5];
  const float* b3 = (const float*)d_in[6];
  const int* actions = (const int*)d_in[7];
  float* out = (float*)d_out;
  char* ws = (char*)d_ws;
  bf16* W1s = (bf16*)(ws + W1S_OFF);
  bf16* W2s = (bf16*)(ws + W2S_OFF);
  int* perm = (int*)(ws + PERM_OFF);
  int* meta = (int*)(ws + META_OFF);

  k_prep<<<2049, 256, 0, stream>>>(W1, W2, W1s, W2s, actions, meta, perm);
  hipFuncSetAttribute((const void*)k_main, hipFuncAttributeMaxDynamicSharedMemorySize, 87040);
  k_main<<<256, 1024, 87040, stream>>>(state, b1, b2, W3, b3, W1s, W2s, perm, meta, out);
}